// Round 9
// baseline (216.194 us; speedup 1.0000x reference)
//
#include <hip/hip_runtime.h>
#include <hip/hip_bf16.h>
#include <math.h>

// Problem constants: B=2, Cin=Cout=32, D=H=W=32, 3x3x3 conv pad 1, 8 directions.
#define NB 2
#define NC 32
#define DD 32
#define VOL (DD*DD*DD)            // 32768
#define WDIR (NC*NC*27)           // 27648 floats per direction per gate
#define BUF_ELEMS (NB*VOL*NC)     // 2097152 elements per channel-last buffer (per dir)
#define WT_DIR (27*96*32)         // 82944 bf16 per direction (transposed weights)

typedef __attribute__((ext_vector_type(8))) short short8;   // 8 bf16 = 4 VGPRs
typedef __attribute__((ext_vector_type(16))) float f32x16;  // 32x32 MFMA accumulator

__device__ __forceinline__ short f2bf(float v) {
    unsigned u = __float_as_uint(v);
    unsigned r = (u + 0x7fffu + ((u >> 16) & 1u)) >> 16;   // RNE
    return (short)r;
}
__device__ __forceinline__ float bf2f(short s) {
    return __uint_as_float(((unsigned)(unsigned short)s) << 16);
}
__device__ __forceinline__ float bf2f_lo(unsigned u) {
    return __uint_as_float(u << 16);
}
__device__ __forceinline__ float bf2f_hi(unsigned u) {
    return __uint_as_float(u & 0xffff0000u);
}
__device__ __forceinline__ unsigned pack2(float a, float b) {
    return ((unsigned)(unsigned short)f2bf(a)) | (((unsigned)(unsigned short)f2bf(b)) << 16);
}

// async global->LDS, 16 B per lane; lds dest = wave-uniform base + lane*16
__device__ __forceinline__ void async_copy16(const void* g, void* l) {
    __builtin_amdgcn_global_load_lds(
        (const __attribute__((address_space(1))) unsigned*)g,
        (__attribute__((address_space(3))) unsigned*)l, 16, 0, 0);
}

// ---------------------------------------------------------------------------
// Fused prep: blocks [0,2048) transpose x -> xT bf16 channel-last;
// blocks [2048,4640) transpose weights -> Wt bf16 [dir][tap][g*32+co][ci].
__global__ __launch_bounds__(256) void prep_xw(
    const float* __restrict__ x,
    const float* __restrict__ Wh, const float* __restrict__ Wz,
    const float* __restrict__ Ws,
    short* __restrict__ xT, short* __restrict__ Wt)
{
    __shared__ float tl[32][33];
    if (blockIdx.x < 2048) {
        const int blk = blockIdx.x;
        const int b = blk >> 10;
        const int i = (blk >> 5) & 31;
        const int j = blk & 31;

        const int k  = threadIdx.x & 31;
        const int cq = threadIdx.x >> 5;
        #pragma unroll
        for (int t = 0; t < 4; ++t) {
            const int ci = cq * 4 + t;
            tl[ci][k] = x[(((b*NC + ci)*DD + i)*DD + j)*DD + k];
        }
        __syncthreads();
        const int ci2 = threadIdx.x & 31;
        const int kq  = threadIdx.x >> 5;
        const int base = ((b*DD + i)*DD + j)*DD*NC;
        #pragma unroll
        for (int t = 0; t < 4; ++t) {
            const int kk = kq * 4 + t;
            xT[base + kk*NC + ci2] = f2bf(tl[ci2][kk]);
        }
    } else {
        const int idx = (blockIdx.x - 2048) * 256 + threadIdx.x;  // 663552 total
        if (idx >= 8*WT_DIR) return;
        const int ci  = idx & 31;
        const int n   = (idx >> 5) % 96;
        const int tap = (idx / (96*32)) % 27;
        const int dir = idx / WT_DIR;
        const int g   = n >> 5;
        const int co  = n & 31;
        const float* W = (g == 0) ? Wh : (g == 1) ? Wz : Ws;
        Wt[idx] = f2bf(W[dir*WDIR + (co*NC + ci)*27 + tap]);
    }
}

// ---------------------------------------------------------------------------
// Fused MFMA conv, 32x32x16 shape.  ONE dir per block, 2048 blocks.
// Block = (b, 2 i's, 4 j's): M=256 voxels (8 j-rows of 32 kv) x N=96.
// Each of 4 waves owns 2 m-tiles (= 2 j-rows) x all 3 n-tiles:
//   MFMA/wave 324 (vs 648 16x16), ds_read_b128/wave 108 (vs 216),
//   regs/wave ~96 AGPR + ~60 VGPR -> 3 waves/SIMD; LDS 52.2 KB -> 3 blocks/CU.
// LDS A-tile uses a 16B-granule XOR swizzle  g = kvr*4 + (ciq ^ (kvr&3))
// making the 32x32 A-fragment reads bank-conflict-free; the staging gptr
// absorbs the permutation (per-lane global addr is free, LDS dest stays
// wave-uniform + lane*16).
// MFMA called as (B, A, acc): D[m=channel][n=voxel]; C/D row mapping
// (reg&3)+8*(reg>>2)+4*(lane>>5) gives 4 consecutive channels per reg-quad
// -> packed 8B stores.  Exactly ONE __syncthreads.
__global__ __launch_bounds__(256, 3) void conv_mfma(
    const short* __restrict__ xT, const short* __restrict__ Wt,
    const float* __restrict__ bh, const float* __restrict__ bz,
    const float* __restrict__ bs,
    short* __restrict__ bufh, short* __restrict__ bufz, short* __restrict__ bufs)
{
    __shared__ __align__(16) short As[24*34*32];     // 52,224 B

    const int tid  = threadIdx.x;
    const int lane = tid & 63;
    const int w    = tid >> 6;
    const int kv   = lane & 31;    // voxel k within j-row  (MFMA n / C-D col)
    const int hl   = lane >> 5;    // k-half selector for fragments

    const int blk = blockIdx.x;    // 2048 = dir(8) x b(2) x ih(16) x jq(8)
    const int j0  = (blk & 7) * 4;
    const int i0  = ((blk >> 3) & 15) * 2;
    const int b   = (blk >> 7) & 1;
    const int dir = blk >> 8;

    // ---- zero k-edge granules (kvr=0 -> g 0..3, kvr=33 -> g 132..135) ----
    if (tid < 192) {
        const int row = tid >> 3;
        const int e   = tid & 7;
        const int g   = (e < 4) ? e : (128 + e);
        *(short8*)((char*)As + row*2176 + g*16) = short8{};
    }
    // ---- stage interior (swizzled gptr) / zero invalid halo rows ----
    for (int t = w; t < 48; t += 4) {               // 24 rows x 2 halves of 1 KB
        const int row = t >> 1;
        const int h   = t & 1;
        const int rr = row / 6, jc = row - rr*6;    // ii_rel 0..3, jj_rel 0..5
        const int ii = i0 + rr - 1, jj = j0 + jc - 1;
        char* ldst = (char*)As + row*2176 + (1 + 16*h)*64 + lane*16;
        if ((unsigned)ii < 32u && (unsigned)jj < 32u) {
            const int kvs = 16*h + (lane >> 2);
            const int cq  = (lane & 3) ^ ((kvs + 1) & 3);
            const char* gp = (const char*)(xT + (((b*DD + ii)*DD + jj)*DD)*NC)
                             + kvs*64 + cq*16;
            async_copy16(gp, ldst);
        } else {
            *(short8*)ldst = short8{};
        }
    }
    __syncthreads();   // the ONLY barrier

    // lane-fixed B base: Wt element (tap*96 + nt*32 + kv)*32 + kc*16 + hl*8
    const short* __restrict__ Wb = Wt + dir*WT_DIR + kv*32 + hl*8;

    // ---- init accumulators with bias: channel = (r&3) + 8*(r>>2) + 4*hl ----
    f32x16 acc[2][3];
    #pragma unroll
    for (int nt = 0; nt < 3; ++nt) {
        #pragma unroll
        for (int r = 0; r < 16; ++r) {
            const int ch = (r & 3) + 8*(r >> 2) + 4*hl;
            const float bv = (nt == 0) ? bh[dir*NC + ch]
                           : (nt == 1) ? bz[dir*NC + ch] : bs[dir*NC + ch];
            acc[0][nt][r] = bv;
            acc[1][nt][r] = bv;
        }
    }

    const int rid0 = w*2,     idd0 = rid0 >> 2, jd0 = rid0 & 3;
    const int rid1 = w*2 + 1, idd1 = rid1 >> 2, jd1 = rid1 & 3;

    // ---- main loop: 9 (ri,rj) groups x 3 rk x 2 k-chunks ----
    #pragma unroll
    for (int g9 = 0; g9 < 9; ++g9) {
        const int ri = g9 / 3, rj = g9 - 3*ri;
        const int arow0 = ((idd0 + ri)*6 + jd0 + rj) * 2176;
        const int arow1 = ((idd1 + ri)*6 + jd1 + rj) * 2176;
        #pragma unroll
        for (int rk = 0; rk < 3; ++rk) {
            const int kvr   = kv + rk;
            const int kvr64 = kvr * 64;
            const int xr    = kvr & 3;
            const short* wp0 = Wb + (g9*3 + rk)*3072;
            #pragma unroll
            for (int kc = 0; kc < 2; ++kc) {
                const int perm = ((kc*2 + hl) ^ xr) * 16;
                const short8 a0 = *(const short8*)((const char*)As + arow0 + kvr64 + perm);
                const short8 a1 = *(const short8*)((const char*)As + arow1 + kvr64 + perm);
                const short8 b0 = *(const short8*)&wp0[kc*16];
                const short8 b1 = *(const short8*)&wp0[1024 + kc*16];
                const short8 b2 = *(const short8*)&wp0[2048 + kc*16];
                acc[0][0] = __builtin_amdgcn_mfma_f32_32x32x16_bf16(b0, a0, acc[0][0], 0, 0, 0);
                acc[1][0] = __builtin_amdgcn_mfma_f32_32x32x16_bf16(b0, a1, acc[1][0], 0, 0, 0);
                acc[0][1] = __builtin_amdgcn_mfma_f32_32x32x16_bf16(b1, a0, acc[0][1], 0, 0, 0);
                acc[1][1] = __builtin_amdgcn_mfma_f32_32x32x16_bf16(b1, a1, acc[1][1], 0, 0, 0);
                acc[0][2] = __builtin_amdgcn_mfma_f32_32x32x16_bf16(b2, a0, acc[0][2], 0, 0, 0);
                acc[1][2] = __builtin_amdgcn_mfma_f32_32x32x16_bf16(b2, a1, acc[1][2], 0, 0, 0);
            }
        }
    }

    // ---- epilogue: D col = voxel kv, row = channel; packed 8B stores ----
    #pragma unroll
    for (int nt = 0; nt < 3; ++nt) {
        short* __restrict__ dst = ((nt == 0) ? bufh : (nt == 1) ? bufz : bufs)
                                  + (size_t)dir * BUF_ELEMS;
        #pragma unroll
        for (int mt = 0; mt < 2; ++mt) {
            const int rid = w*2 + mt;
            const int i = i0 + (rid >> 2);
            const int j = j0 + (rid & 3);
            const int base = (((b*DD + i)*DD + j)*DD + kv)*NC + 4*hl;
            #pragma unroll
            for (int q = 0; q < 4; ++q) {
                float v0 = acc[mt][nt][4*q + 0], v1 = acc[mt][nt][4*q + 1];
                float v2 = acc[mt][nt][4*q + 2], v3 = acc[mt][nt][4*q + 3];
                if (nt != 0) {
                    v0 = 1.0f/(1.0f + __expf(-v0)); v1 = 1.0f/(1.0f + __expf(-v1));
                    v2 = 1.0f/(1.0f + __expf(-v2)); v3 = 1.0f/(1.0f + __expf(-v3));
                }
                uint2 pk = { pack2(v0, v1), pack2(v2, v3) };
                *(uint2*)&dst[base + 8*q] = pk;
            }
        }
    }
}

// ---------------------------------------------------------------------------
// Fused diagonal GRU scan: ALL 8 directions in one dispatch (blockIdx.z = dir).
// Writes contrib = o*s (bf16) to the separate cont buffer. 4 channels per lane
// via uint2: 8 lanes per chain.
__global__ __launch_bounds__(256) void gru_scan(
    const short* __restrict__ bufh, const short* __restrict__ bufz,
    const short* __restrict__ bufs, short* __restrict__ cont,
    const float* __restrict__ h0)
{
    const int dir = blockIdx.z;
    const int di = (dir & 4) ? 1 : -1;
    const int dj = (dir & 2) ? 1 : -1;
    const int dk = (dir & 1) ? 1 : -1;
    const size_t doff = (size_t)dir * BUF_ELEMS;
    const short* __restrict__ bh_ = bufh + doff;
    const short* __restrict__ bz_ = bufz + doff;
    const short* __restrict__ bs_ = bufs + doff;
    short* __restrict__ ct_ = cont + doff;

    const int c8   = threadIdx.x & 7;      // channel quad: channels 4*c8..4*c8+3
    const int slot = threadIdx.x >> 3;     // 32 chains per block
    const int cid  = blockIdx.x * 32 + slot;
    if (cid >= 2977) return;
    const int b = blockIdx.y;

    int ic, jc, kc;
    if (cid < 1024)      { ic = 0;             jc = cid >> 5;      kc = cid & 31; }
    else if (cid < 2016) { int t = cid - 1024; ic = 1 + (t >> 5);  jc = 0; kc = t & 31; }
    else                 { int t = cid - 2016; int q = t / 31;
                           ic = 1 + q;         jc = 1 + (t - q*31); kc = 0; }

    int mx = ic > jc ? ic : jc; if (kc > mx) mx = kc;
    const int L  = 32 - mx;
    const int i0 = (di > 0) ? ic : 31 - ic;
    const int j0 = (dj > 0) ? jc : 31 - jc;
    const int k0 = (dk > 0) ? kc : 31 - kc;
    const int step = di*(DD*DD*NC) + dj*(DD*NC) + dk*NC;

    int p = b*(VOL*NC) + i0*(DD*DD*NC) + j0*(DD*NC) + k0*NC + c8*4;
    float p0 = h0[dir*NC + c8*4 + 0];
    float p1 = h0[dir*NC + c8*4 + 1];
    float p2 = h0[dir*NC + c8*4 + 2];
    float p3 = h0[dir*NC + c8*4 + 3];

    for (int s = 0; s < L; ++s) {
        const uint2 uz = *(const uint2*)&bz_[p];
        const uint2 uh = *(const uint2*)&bh_[p];
        const uint2 us = *(const uint2*)&bs_[p];

        const float z0 = bf2f_lo(uz.x), z1 = bf2f_hi(uz.x);
        const float z2 = bf2f_lo(uz.y), z3 = bf2f_hi(uz.y);
        const float h0v = bf2f_lo(uh.x), h1v = bf2f_hi(uh.x);
        const float h2v = bf2f_lo(uh.y), h3v = bf2f_hi(uh.y);
        const float s0 = bf2f_lo(us.x), s1 = bf2f_hi(us.x);
        const float s2 = bf2f_lo(us.y), s3 = bf2f_hi(us.y);

        const float o0 = z0*h0v + (1.0f - z0)*p0;
        const float o1 = z1*h1v + (1.0f - z1)*p1;
        const float o2 = z2*h2v + (1.0f - z2)*p2;
        const float o3 = z3*h3v + (1.0f - z3)*p3;

        uint2 pk = { pack2(o0*s0, o1*s1), pack2(o2*s2, o3*s3) };
        *(uint2*)&ct_[p] = pk;

        p0 = o0; p1 = o1; p2 = o2; p3 = o3;
        p += step;
    }
}

// ---------------------------------------------------------------------------
// Sum 8 dir contribs (bf16, channel-last) and transpose -> out (b,c,i,j,k) fp32.
__global__ __launch_bounds__(256) void transpose_out(
    const short* __restrict__ contrib, float* __restrict__ out)
{
    __shared__ float tl[32][33];
    const int blk = blockIdx.x;
    const int b = blk >> 10;
    const int i = (blk >> 5) & 31;
    const int j = blk & 31;

    const int c  = threadIdx.x & 31;
    const int kq = threadIdx.x >> 5;
    const int base = ((b*DD + i)*DD + j)*DD*NC;
    #pragma unroll
    for (int t = 0; t < 4; ++t) {
        const int k = kq*4 + t;
        float s = 0.0f;
        #pragma unroll
        for (int d = 0; d < 8; ++d)
            s += bf2f(contrib[(size_t)d*BUF_ELEMS + base + k*NC + c]);
        tl[k][c] = s;
    }
    __syncthreads();

    const int k2 = threadIdx.x & 31;
    const int cq = threadIdx.x >> 5;
    const int obase = b*(NC*VOL) + i*(DD*DD) + j*DD;
    #pragma unroll
    for (int t = 0; t < 4; ++t) {
        const int co = cq*4 + t;
        out[obase + co*VOL + k2] = tl[k2][co];
    }
}

// ---------------------------------------------------------------------------
extern "C" void kernel_launch(void* const* d_in, const int* in_sizes, int n_in,
                              void* d_out, int out_size, void* d_ws, size_t ws_size,
                              hipStream_t stream)
{
    const float* x  = (const float*)d_in[0];
    const float* Wh = (const float*)d_in[1];
    const float* bh = (const float*)d_in[2];
    const float* Wz = (const float*)d_in[3];
    const float* bz = (const float*)d_in[4];
    const float* Ws = (const float*)d_in[5];
    const float* bs = (const float*)d_in[6];
    const float* h0 = (const float*)d_in[7];
    float* out = (float*)d_out;

    // Workspace layout (~140 MB total):
    short* bufh = (short*)d_ws;                          // 8 dirs x 4 MB bf16
    short* bufz = bufh + 8*(size_t)BUF_ELEMS;            // 33.5 MB
    short* bufs = bufz + 8*(size_t)BUF_ELEMS;            // 33.5 MB
    short* xT   = bufs + 8*(size_t)BUF_ELEMS;            // 4 MB bf16 channel-last x
    short* Wt   = xT + BUF_ELEMS;                        // 1.33 MB bf16 weights (8 dirs)
    short* cont = Wt + 8*(size_t)WT_DIR;                 // 8 dirs x 4 MB bf16 contribs

    // Fused input/weight transposes (one dispatch).
    prep_xw<<<2048 + (8*WT_DIR + 255)/256, 256, 0, stream>>>(x, Wh, Wz, Ws, xT, Wt);

    // One conv dispatch for all 8 directions (one dir per block, 32x32 MFMA).
    conv_mfma<<<2048, 256, 0, stream>>>(xT, Wt, bh, bz, bs, bufh, bufz, bufs);

    // One fused scan dispatch for all 8 directions (contribs into cont).
    gru_scan<<<dim3((2977 + 31)/32, NB, 8), 256, 0, stream>>>(bufh, bufz, bufs, cont, h0);

    // Sum dirs + transpose.
    transpose_out<<<NB*DD*DD, 256, 0, stream>>>(cont, out);
}